// Round 4
// baseline (617.690 us; speedup 1.0000x reference)
//
#include <hip/hip_runtime.h>
#include <cstddef>

constexpr int B = 2, H = 16, S = 2048, D = 128;
constexpr int BH = B * H;
constexpr int TWOD = 2 * D;          // 256
constexpr int QTILE = 128;           // q rows per block: 4 waves x 2 mtiles x 16
constexpr int BC = 32;               // keys per tile
constexpr int NKT = S / BC;          // 64
constexpr float SC2 = 0.08838834764831845f * 1.4426950408889634f; // (1/sqrt(128))*log2(e)
constexpr float LAM_INIT = 0.8f;
constexpr float GN_EPS = 1e-5f;

typedef __attribute__((ext_vector_type(8))) short short8;
typedef __attribute__((ext_vector_type(4))) float f32x4;

__device__ __forceinline__ unsigned short f2b(float f) {
  unsigned int u = __float_as_uint(f);
  u += 0x7fffu + ((u >> 16) & 1u);
  return (unsigned short)(u >> 16);
}

__device__ __forceinline__ void async_copy16(const void* g, void* l) {
  typedef __attribute__((address_space(1))) const void gvoid;
  typedef __attribute__((address_space(3))) void lvoid;
  __builtin_amdgcn_global_load_lds((gvoid*)g, (lvoid*)l, 16, 0, 0);
}

// ---------------- kernel 0: fused prep ----------------
// grid (S/64, BH): per block convert K rows [s0,s0+64) fp32->bf16 and
// transpose V [s0,s0+64)x128 -> vtg [bh][d][s] bf16. Block (0,0) also
// computes lambda into wsf[0].
__global__ void prep_kernel(const float* __restrict__ k, const float* __restrict__ v,
                            const float* __restrict__ lq1, const float* __restrict__ lq2,
                            const float* __restrict__ lk1, const float* __restrict__ lk2,
                            unsigned short* __restrict__ kbf, unsigned short* __restrict__ vtg,
                            float* __restrict__ wsf) {
  __shared__ float tile[64][129];     // V staging; also reused as lam scratch (first 256 floats)
  const int bh = blockIdx.y, s0 = blockIdx.x * 64, t = threadIdx.x;

  // ---- lambda (block (0,0) only) ----
  if (blockIdx.x == 0 && blockIdx.y == 0) {
    if (t < 128) {
      tile[0][t] = lq1[t] * lk1[t];
      tile[1][t] = lq2[t] * lk2[t];
    }
    __syncthreads();
    if (t == 0) {
      float s1 = 0.f, s2 = 0.f;
      for (int i = 0; i < 128; ++i) { s1 += tile[0][i]; s2 += tile[1][i]; }
      wsf[0] = expf(s1) - expf(s2) + LAM_INIT;
    }
    __syncthreads();
  }

  // ---- K convert: 64 rows x 256 cols, contiguous chunk ----
  {
    const float* ks = k + ((size_t)bh * S + s0) * TWOD;
    unsigned short* kd = kbf + ((size_t)bh * S + s0) * TWOD;
#pragma unroll
    for (int i = 0; i < 8; ++i) {
      size_t off = (size_t)(i * 256 + t) * 8;
      float4 a = *(const float4*)(ks + off);
      float4 b2 = *(const float4*)(ks + off + 4);
      unsigned short u[8];
      u[0] = f2b(a.x); u[1] = f2b(a.y); u[2] = f2b(a.z); u[3] = f2b(a.w);
      u[4] = f2b(b2.x); u[5] = f2b(b2.y); u[6] = f2b(b2.z); u[7] = f2b(b2.w);
      *(uint4*)(kd + off) = *(uint4*)u;
    }
  }

  // ---- V transpose: 64s x 128d -> [d][s] ----
#pragma unroll
  for (int i = 0; i < 8; ++i) {
    int idx = t + i * 256;            // 2048 f4 chunks (64 s x 32 f4)
    int row = idx >> 5, c4 = idx & 31;
    float4 f = *(const float4*)(v + ((size_t)bh * S + s0 + row) * D + c4 * 4);
    tile[row][c4 * 4 + 0] = f.x; tile[row][c4 * 4 + 1] = f.y;
    tile[row][c4 * 4 + 2] = f.z; tile[row][c4 * 4 + 3] = f.w;
  }
  __syncthreads();
#pragma unroll
  for (int i = 0; i < 4; ++i) {
    int c = t + i * 256;              // 1024 chunks (128 d x 8 k-groups)
    int d = c >> 3, k8 = c & 7;
    unsigned short u[8];
#pragma unroll
    for (int j = 0; j < 8; ++j) u[j] = f2b(tile[k8 * 8 + j][d]);
    *(uint4*)(vtg + ((size_t)bh * D + d) * S + s0 + k8 * 8) = *(uint4*)u;
  }
}

// ---------------- kernel 1: dual-stream flash attention, pipelined ----------------
// PV(t-1) overlaps QK(t). V B-frags load directly from global vtg (L2-resident,
// issued at iter top for tile t-1 -> no barrier dependency) — V never touches
// LDS. K via double-buffered global_load_lds DMA. Wave-private Pa round-trip.
__global__ __launch_bounds__(256, 2)
void attn_kernel(const float* __restrict__ q, const unsigned short* __restrict__ kbf,
                 const unsigned short* __restrict__ vtg,
                 float* __restrict__ wsf, float* __restrict__ out) {
  __shared__ __attribute__((aligned(16))) unsigned short Ks[2][32][256];  // async dest, chunk-swizzled
  __shared__ __attribute__((aligned(16))) unsigned short Pa[4][2][32][40];// wave-private, swizzled
  __shared__ float sred[4][2];

  const int bh = blockIdx.x, qb = blockIdx.y;
  const int q0 = qb * QTILE;
  const int tid = threadIdx.x;
  const int wave = tid >> 6, lane = tid & 63;
  const int quad = lane >> 4, l16 = lane & 15;
  const float lam = wsf[0];

  // ---- register-resident bf16 Q fragments (A-layout) ----
  short8 qf[2][2][4];                 // [mtile][stream][kstep]
#pragma unroll
  for (int mt = 0; mt < 2; ++mt) {
    int qrow = q0 + wave * 32 + mt * 16 + l16;
    const float* qr = q + ((size_t)bh * S + qrow) * TWOD;
#pragma unroll
    for (int st = 0; st < 2; ++st)
#pragma unroll
      for (int ks = 0; ks < 4; ++ks) {
        const float* p = qr + st * D + ks * 32 + quad * 8;
        float4 f0 = *(const float4*)p;
        float4 f1 = *(const float4*)(p + 4);
        short8 v8;
        v8[0] = (short)f2b(f0.x); v8[1] = (short)f2b(f0.y);
        v8[2] = (short)f2b(f0.z); v8[3] = (short)f2b(f0.w);
        v8[4] = (short)f2b(f1.x); v8[5] = (short)f2b(f1.y);
        v8[6] = (short)f2b(f1.z); v8[7] = (short)f2b(f1.w);
        qf[mt][st][ks] = v8;
      }
  }

  // ---- staging addresses ----
  const unsigned short* kbase = kbf + (size_t)bh * S * (size_t)TWOD;
  int goff[4];
#pragma unroll
  for (int i = 0; i < 4; ++i) {
    int L = i * 256 + tid;
    int row = L >> 5, cp = L & 31;
    int g = cp ^ (row & 7);
    goff[i] = row * 256 + g * 8;
  }
  // V B-frag base for this lane: row (nt8*16+l16), key offset quad*8
  const unsigned short* vlane = vtg + ((size_t)bh * D + l16) * S + quad * 8;

  f32x4 acc[2][2][8];
#pragma unroll
  for (int mt = 0; mt < 2; ++mt)
#pragma unroll
    for (int st = 0; st < 2; ++st)
#pragma unroll
      for (int n = 0; n < 8; ++n) acc[mt][st][n] = (f32x4){0.f, 0.f, 0.f, 0.f};
  float lacc[2][2][4];
#pragma unroll
  for (int mt = 0; mt < 2; ++mt)
#pragma unroll
    for (int st = 0; st < 2; ++st)
#pragma unroll
      for (int r = 0; r < 4; ++r) lacc[mt][st][r] = 0.f;

  const int pa_rd_off = (quad ^ ((l16 >> 2) & 3)) * 8;

  auto qk = [&](int st, int kb, f32x4 (&sa)[2][2]) {
#pragma unroll
    for (int nt = 0; nt < 2; ++nt) {
      const int row = nt * 16 + l16;
      const int rx = row & 7;
#pragma unroll
      for (int ks = 0; ks < 4; ++ks) {
        const int pos = (st * 16 + ks * 4 + quad) ^ rx;
        const short8 kf = *(const short8*)&Ks[kb][row][pos * 8];
        sa[0][nt] = __builtin_amdgcn_mfma_f32_16x16x32_bf16(qf[0][st][ks], kf, sa[0][nt], 0, 0, 0);
        sa[1][nt] = __builtin_amdgcn_mfma_f32_16x16x32_bf16(qf[1][st][ks], kf, sa[1][nt], 0, 0, 0);
      }
    }
  };
  auto pexp = [&](int st, f32x4 (&sa)[2][2]) {
#pragma unroll
    for (int mt = 0; mt < 2; ++mt)
#pragma unroll
      for (int nt = 0; nt < 2; ++nt)
#pragma unroll
        for (int r = 0; r < 4; ++r) {
          float p = __builtin_amdgcn_exp2f(sa[mt][nt][r] * SC2);
          lacc[mt][st][r] += p;
          int colp = (((nt * 2) + (l16 >> 3)) ^ quad) * 8 + (l16 & 7);
          Pa[wave][st][mt * 16 + quad * 4 + r][colp] = f2b(p);
        }
  };
  auto pv = [&](int st, const short8 (&paf)[2], const short8 (&vf)[8]) {
#pragma unroll
    for (int nt8 = 0; nt8 < 8; ++nt8)
#pragma unroll
      for (int mt = 0; mt < 2; ++mt)
        acc[mt][st][nt8] = __builtin_amdgcn_mfma_f32_16x16x32_bf16(paf[mt], vf[nt8], acc[mt][st][nt8], 0, 0, 0);
  };

  // ---- prologue: zero Pa (PV(-1) contributes exact zeros), stage K tile 0 ----
  {
    const uint4 z = {0u, 0u, 0u, 0u};
    unsigned short* pz = &Pa[0][0][0][0];
    for (int i = tid; i < 1280; i += 256) *(uint4*)(pz + i * 8) = z;
#pragma unroll
    for (int i = 0; i < 4; ++i)
      async_copy16(kbase + goff[i], &Ks[0][0][0] + (i * 256 + tid) * 8);
  }
  __syncthreads();

  for (int t = 0; t < NKT; ++t) {
    const int kbuf = t & 1;
    const int nbuf = kbuf ^ 1;

    // ---- V(t-1) B-frags direct from global (issued first for latency cover) ----
    const int tv = (t == 0) ? 0 : (t - 1);
    short8 vf[8];
#pragma unroll
    for (int nt8 = 0; nt8 < 8; ++nt8)
      vf[nt8] = *(const short8*)(vlane + (size_t)(nt8 * 16) * S + tv * BC);

    // ---- P(t-1) A-frags from wave-private LDS ----
    short8 paf[2][2];
#pragma unroll
    for (int st = 0; st < 2; ++st)
#pragma unroll
      for (int mt = 0; mt < 2; ++mt)
        paf[st][mt] = *(const short8*)&Pa[wave][st][mt * 16 + l16][pa_rd_off];

    // ---- K(t+1) DMA into the other buffer ----
    if (t + 1 < NKT) {
      const unsigned short* kp = kbase + (size_t)(t + 1) * BC * TWOD;
      unsigned short* ldsb = &Ks[nbuf][0][0];
#pragma unroll
      for (int i = 0; i < 4; ++i)
        async_copy16(kp + goff[i], ldsb + (i * 256 + tid) * 8);
    }

    // ---- pipelined compute: QK(t) interleaved with PV(t-1) ----
    f32x4 sa0[2][2], sa1[2][2];
#pragma unroll
    for (int mt = 0; mt < 2; ++mt)
#pragma unroll
      for (int nt = 0; nt < 2; ++nt) {
        sa0[mt][nt] = (f32x4){0.f, 0.f, 0.f, 0.f};
        sa1[mt][nt] = (f32x4){0.f, 0.f, 0.f, 0.f};
      }
    qk(0, kbuf, sa0);
    pv(0, paf[0], vf);
    pexp(0, sa0);
    qk(1, kbuf, sa1);
    pv(1, paf[1], vf);
    pexp(1, sa1);

    __syncthreads();                 // drains K(t+1) DMA; fences Ks buffer reuse
  }

  // ---- epilogue PV(NKT-1) ----
  {
    short8 paf[2][2], vf[8];
#pragma unroll
    for (int nt8 = 0; nt8 < 8; ++nt8)
      vf[nt8] = *(const short8*)(vlane + (size_t)(nt8 * 16) * S + (NKT - 1) * BC);
#pragma unroll
    for (int st = 0; st < 2; ++st)
#pragma unroll
      for (int mt = 0; mt < 2; ++mt)
        paf[st][mt] = *(const short8*)&Pa[wave][st][mt * 16 + l16][pa_rd_off];
    pv(0, paf[0], vf);
    pv(1, paf[1], vf);
  }

  // ---- softmax denominators ----
#pragma unroll
  for (int mt = 0; mt < 2; ++mt)
#pragma unroll
    for (int st = 0; st < 2; ++st)
#pragma unroll
      for (int r = 0; r < 4; ++r) {
        float v = lacc[mt][st][r];
        v += __shfl_xor(v, 1, 16);
        v += __shfl_xor(v, 2, 16);
        v += __shfl_xor(v, 4, 16);
        v += __shfl_xor(v, 8, 16);
        lacc[mt][st][r] = v;
      }

  float sum = 0.f, ssq = 0.f;
#pragma unroll
  for (int mt = 0; mt < 2; ++mt) {
    float i1[4], i2[4];
#pragma unroll
    for (int r = 0; r < 4; ++r) {
      i1[r] = 1.f / lacc[mt][0][r];
      i2[r] = lam / lacc[mt][1][r];
    }
#pragma unroll
    for (int nt8 = 0; nt8 < 8; ++nt8)
#pragma unroll
      for (int r = 0; r < 4; ++r) {
        float o = acc[mt][0][nt8][r] * i1[r] - acc[mt][1][nt8][r] * i2[r];
        int row = q0 + wave * 32 + mt * 16 + quad * 4 + r;
        out[((size_t)bh * S + row) * D + nt8 * 16 + l16] = o;
        sum += o; ssq += o * o;
      }
  }
#pragma unroll
  for (int off = 32; off >= 1; off >>= 1) {
    sum += __shfl_xor(sum, off, 64);
    ssq += __shfl_xor(ssq, off, 64);
  }
  if (lane == 0) { sred[wave][0] = sum; sred[wave][1] = ssq; }
  __syncthreads();
  if (tid == 0) {
    float s0 = sred[0][0] + sred[1][0] + sred[2][0] + sred[3][0];
    float s1 = sred[0][1] + sred[1][1] + sred[2][1] + sred[3][1];
    int idx = bh * 16 + qb;
    wsf[64 + idx * 2] = s0;
    wsf[64 + idx * 2 + 1] = s1;
  }
}

// ---------------- kernel 2: group norm (in-place on out) ----------------
// grid (BH, 32)
__global__ void gn_kernel(float* __restrict__ out, const float* __restrict__ gw,
                          const float* __restrict__ gb, const float* __restrict__ wsf) {
  const int bh = blockIdx.x, part = blockIdx.y;
  const int h = bh & (H - 1);
  float sum = 0.f, ssq = 0.f;
  for (int j = 0; j < 16; ++j) {
    sum += wsf[64 + (bh * 16 + j) * 2];
    ssq += wsf[64 + (bh * 16 + j) * 2 + 1];
  }
  const float invn = 1.f / (float)(S * D);
  const float mean = sum * invn;
  const float var = ssq * invn - mean * mean;
  const float rstd = rsqrtf(var + GN_EPS);
  const float outscale = 1.f - LAM_INIT;
  const float4* g4 = (const float4*)(gw + h * D);
  const float4* b4 = (const float4*)(gb + h * D);
  float4* o4 = (float4*)(out + (size_t)bh * S * D);
  const int chunks_per = (S * D / 4) / 32;   // 2048
  const int c0 = part * chunks_per;
  for (int c = c0 + threadIdx.x; c < c0 + chunks_per; c += 256) {
    float4 vv = o4[c];
    int d4 = c & 31;
    float4 g = g4[d4], bb = b4[d4];
    vv.x = ((vv.x - mean) * rstd * g.x + bb.x) * outscale;
    vv.y = ((vv.y - mean) * rstd * g.y + bb.y) * outscale;
    vv.z = ((vv.z - mean) * rstd * g.z + bb.z) * outscale;
    vv.w = ((vv.w - mean) * rstd * g.w + bb.w) * outscale;
    o4[c] = vv;
  }
}

extern "C" void kernel_launch(void* const* d_in, const int* in_sizes, int n_in,
                              void* d_out, int out_size, void* d_ws, size_t ws_size,
                              hipStream_t stream) {
  (void)in_sizes; (void)n_in; (void)out_size; (void)ws_size;
  const float* q   = (const float*)d_in[0];
  const float* k   = (const float*)d_in[1];
  const float* v   = (const float*)d_in[2];
  const float* lq1 = (const float*)d_in[3];
  const float* lq2 = (const float*)d_in[4];
  const float* lk1 = (const float*)d_in[5];
  const float* lk2 = (const float*)d_in[6];
  const float* gw  = (const float*)d_in[7];
  const float* gb  = (const float*)d_in[8];
  float* out = (float*)d_out;
  float* wsf = (float*)d_ws;
  unsigned short* vtg = (unsigned short*)((char*)d_ws + 8192);
  unsigned short* kbf = (unsigned short*)((char*)d_ws + 8192 + (size_t)BH * D * S * 2);

  prep_kernel<<<dim3(S / 64, BH), dim3(256), 0, stream>>>(k, v, lq1, lq2, lk1, lk2, kbf, vtg, wsf);
  attn_kernel<<<dim3(BH, S / QTILE), dim3(256), 0, stream>>>(q, kbf, vtg, wsf, out);
  gn_kernel<<<dim3(BH, 32), dim3(256), 0, stream>>>(out, gw, gb, wsf);
}

// Round 5
// 455.455 us; speedup vs baseline: 1.3562x; 1.3562x over previous
//
#include <hip/hip_runtime.h>
#include <cstddef>

constexpr int B = 2, H = 16, S = 2048, D = 128;
constexpr int BH = B * H;
constexpr int TWOD = 2 * D;          // 256
constexpr int QTILE = 128;           // q rows per block: 4 waves x 2 mtiles x 16
constexpr int BC = 32;               // keys per tile
constexpr int NKT = S / BC;          // 64
constexpr float SC2 = 0.08838834764831845f * 1.4426950408889634f; // (1/sqrt(128))*log2(e)
constexpr float LAM_INIT = 0.8f;
constexpr float GN_EPS = 1e-5f;

typedef __attribute__((ext_vector_type(8))) short short8;
typedef __attribute__((ext_vector_type(4))) float f32x4;

__device__ __forceinline__ unsigned short f2b(float f) {
  unsigned int u = __float_as_uint(f);
  u += 0x7fffu + ((u >> 16) & 1u);
  return (unsigned short)(u >> 16);
}

__device__ __forceinline__ void async_copy16(const void* g, void* l) {
  typedef __attribute__((address_space(1))) const void gvoid;
  typedef __attribute__((address_space(3))) void lvoid;
  __builtin_amdgcn_global_load_lds((gvoid*)g, (lvoid*)l, 16, 0, 0);
}

// ---------------- kernel 0: fused prep (lam + K bf16 + V^T bf16) ----------------
__global__ void prep_kernel(const float* __restrict__ k, const float* __restrict__ v,
                            const float* __restrict__ lq1, const float* __restrict__ lq2,
                            const float* __restrict__ lk1, const float* __restrict__ lk2,
                            unsigned short* __restrict__ kbf, unsigned short* __restrict__ vtg,
                            float* __restrict__ wsf) {
  __shared__ float tile[64][129];
  const int bh = blockIdx.y, s0 = blockIdx.x * 64, t = threadIdx.x;

  if (blockIdx.x == 0 && blockIdx.y == 0) {
    if (t < 128) {
      tile[0][t] = lq1[t] * lk1[t];
      tile[1][t] = lq2[t] * lk2[t];
    }
    __syncthreads();
    if (t == 0) {
      float s1 = 0.f, s2 = 0.f;
      for (int i = 0; i < 128; ++i) { s1 += tile[0][i]; s2 += tile[1][i]; }
      wsf[0] = expf(s1) - expf(s2) + LAM_INIT;
    }
    __syncthreads();
  }

  {
    const float* ks = k + ((size_t)bh * S + s0) * TWOD;
    unsigned short* kd = kbf + ((size_t)bh * S + s0) * TWOD;
#pragma unroll
    for (int i = 0; i < 8; ++i) {
      size_t off = (size_t)(i * 256 + t) * 8;
      float4 a = *(const float4*)(ks + off);
      float4 b2 = *(const float4*)(ks + off + 4);
      unsigned short u[8];
      u[0] = f2b(a.x); u[1] = f2b(a.y); u[2] = f2b(a.z); u[3] = f2b(a.w);
      u[4] = f2b(b2.x); u[5] = f2b(b2.y); u[6] = f2b(b2.z); u[7] = f2b(b2.w);
      *(uint4*)(kd + off) = *(uint4*)u;
    }
  }

#pragma unroll
  for (int i = 0; i < 8; ++i) {
    int idx = t + i * 256;
    int row = idx >> 5, c4 = idx & 31;
    float4 f = *(const float4*)(v + ((size_t)bh * S + s0 + row) * D + c4 * 4);
    tile[row][c4 * 4 + 0] = f.x; tile[row][c4 * 4 + 1] = f.y;
    tile[row][c4 * 4 + 2] = f.z; tile[row][c4 * 4 + 3] = f.w;
  }
  __syncthreads();
#pragma unroll
  for (int i = 0; i < 4; ++i) {
    int c = t + i * 256;
    int d = c >> 3, k8 = c & 7;
    unsigned short u[8];
#pragma unroll
    for (int j = 0; j < 8; ++j) u[j] = f2b(tile[k8 * 8 + j][d]);
    *(uint4*)(vtg + ((size_t)bh * D + d) * S + s0 + k8 * 8) = *(uint4*)u;
  }
}

// ---------------- kernel 1: flash attention, drain-free K-loop ----------------
// Every wave DMAs the FULL K and V tile (identical bytes from all waves: benign
// race) so tile-readiness is wave-local via its own vmcnt. Raw s_barrier (no
// memory drain) rotates buffers; tile t+1's 24 DMAs stay in flight across the
// next barrier (vmcnt never drains to 0 mid-loop). PV(t-1) overlaps QK(t);
// Pa wave-private.
__global__ __launch_bounds__(256, 2)
void attn_kernel(const float* __restrict__ q, const unsigned short* __restrict__ kbf,
                 const unsigned short* __restrict__ vtg,
                 float* __restrict__ wsf, float* __restrict__ out) {
  __shared__ __attribute__((aligned(16))) unsigned short Ks[2][8192];   // 32 keys x 256 d, chunk-swizzled
  __shared__ __attribute__((aligned(16))) unsigned short Vt3[3][4096];  // 128 d x 32 keys, chunk-swizzled
  __shared__ __attribute__((aligned(16))) unsigned short Pa[4][2][32][40];
  __shared__ float sred[4][2];

  const int bh = blockIdx.x, qb = blockIdx.y;
  const int q0 = qb * QTILE;
  const int tid = threadIdx.x;
  const int wave = tid >> 6, lane = tid & 63;
  const int quad = lane >> 4, l16 = lane & 15;
  const float lam = wsf[0];

  // ---- register-resident bf16 Q fragments (A-layout) ----
  short8 qf[2][2][4];                 // [mtile][stream][kstep]
#pragma unroll
  for (int mt = 0; mt < 2; ++mt) {
    int qrow = q0 + wave * 32 + mt * 16 + l16;
    const float* qr = q + ((size_t)bh * S + qrow) * TWOD;
#pragma unroll
    for (int st = 0; st < 2; ++st)
#pragma unroll
      for (int ks = 0; ks < 4; ++ks) {
        const float* p = qr + st * D + ks * 32 + quad * 8;
        float4 f0 = *(const float4*)p;
        float4 f1 = *(const float4*)(p + 4);
        short8 v8;
        v8[0] = (short)f2b(f0.x); v8[1] = (short)f2b(f0.y);
        v8[2] = (short)f2b(f0.z); v8[3] = (short)f2b(f0.w);
        v8[4] = (short)f2b(f1.x); v8[5] = (short)f2b(f1.y);
        v8[6] = (short)f2b(f1.z); v8[7] = (short)f2b(f1.w);
        qf[mt][st][ks] = v8;
      }
  }

  // ---- per-lane DMA source offsets (element units) ----
  // K instr j (0..15): chunk L=j*64+lane; row=L>>5 ( = lane>>5 + 2j ); cs=L&31
  // ( = lane&31 ); src chunk c = cs ^ (row&7). koff[j&3] + (j>>2)*2048 covers all j.
  int koff[4];
#pragma unroll
  for (int j = 0; j < 4; ++j) {
    int L = j * 64 + lane;
    int row = L >> 5, cs = L & 31;
    koff[j] = row * 256 + (cs ^ (row & 7)) * 8;
  }
  // V instr j (0..7): chunk L=j*64+lane; d=L>>2 (= lane>>2 + 16j); cs=L&3 (= lane&3);
  // src chunk c = cs ^ (d&3) — constant over j since 16j%4==0. voff + j*32768.
  int voff;
  {
    int d = lane >> 2, cs = lane & 3;
    voff = d * S + (cs ^ (d & 3)) * 8;
  }
  const unsigned short* kbase = kbf + (size_t)bh * S * (size_t)TWOD;
  const unsigned short* vbase = vtg + (size_t)bh * D * (size_t)S;

  f32x4 acc[2][2][8];
#pragma unroll
  for (int mt = 0; mt < 2; ++mt)
#pragma unroll
    for (int st = 0; st < 2; ++st)
#pragma unroll
      for (int n = 0; n < 8; ++n) acc[mt][st][n] = (f32x4){0.f, 0.f, 0.f, 0.f};
  float lacc[2][2][4];
#pragma unroll
  for (int mt = 0; mt < 2; ++mt)
#pragma unroll
    for (int st = 0; st < 2; ++st)
#pragma unroll
      for (int r = 0; r < 4; ++r) lacc[mt][st][r] = 0.f;

  const int pa_rd_off = (quad ^ ((l16 >> 2) & 3)) * 8;
  // V read: logical (d = nt8*16+l16, chunk quad) at slot d*32 + (quad^(d&3))*8
  const int vro = l16 * 32 + ((quad ^ (l16 & 3)) * 8);

  auto qk = [&](int st, int kb, f32x4 (&sa)[2][2]) {
#pragma unroll
    for (int nt = 0; nt < 2; ++nt) {
      const int row = nt * 16 + l16;
      const int rx = row & 7;
#pragma unroll
      for (int ks = 0; ks < 4; ++ks) {
        const int pos = (st * 16 + ks * 4 + quad) ^ rx;
        const short8 kf = *(const short8*)&Ks[kb][row * 256 + pos * 8];
        sa[0][nt] = __builtin_amdgcn_mfma_f32_16x16x32_bf16(qf[0][st][ks], kf, sa[0][nt], 0, 0, 0);
        sa[1][nt] = __builtin_amdgcn_mfma_f32_16x16x32_bf16(qf[1][st][ks], kf, sa[1][nt], 0, 0, 0);
      }
    }
  };
  auto pexp = [&](int st, f32x4 (&sa)[2][2]) {
#pragma unroll
    for (int mt = 0; mt < 2; ++mt)
#pragma unroll
      for (int nt = 0; nt < 2; ++nt)
#pragma unroll
        for (int r = 0; r < 4; ++r) {
          float p = __builtin_amdgcn_exp2f(sa[mt][nt][r] * SC2);
          lacc[mt][st][r] += p;
          int colp = (((nt * 2) + (l16 >> 3)) ^ quad) * 8 + (l16 & 7);
          Pa[wave][st][mt * 16 + quad * 4 + r][colp] = f2b(p);
        }
  };
  auto pv = [&](int st, const short8 (&paf)[2], const short8 (&vf)[8]) {
#pragma unroll
    for (int nt8 = 0; nt8 < 8; ++nt8)
#pragma unroll
      for (int mt = 0; mt < 2; ++mt)
        acc[mt][st][nt8] = __builtin_amdgcn_mfma_f32_16x16x32_bf16(paf[mt], vf[nt8], acc[mt][st][nt8], 0, 0, 0);
  };
  auto dma_tile = [&](int t, unsigned short* kd, unsigned short* vd) {
    const unsigned short* kp = kbase + (size_t)t * BC * TWOD;
#pragma unroll
    for (int j = 0; j < 16; ++j)
      async_copy16(kp + koff[j & 3] + (j >> 2) * 2048, kd + j * 512);
    const unsigned short* vp = vbase + t * BC;
#pragma unroll
    for (int j = 0; j < 8; ++j)
      async_copy16(vp + voff + j * 16 * S, vd + j * 512);
  };

  // ---- prologue: zero Pa + Vt3[2] (PV(-1) must multiply finite zeros), DMA tile 0 ----
  {
    const uint4 z = {0u, 0u, 0u, 0u};
    unsigned short* pz = &Pa[0][0][0][0];
    for (int i = tid; i < 1280; i += 256) *(uint4*)(pz + i * 8) = z;
    unsigned short* vz = &Vt3[2][0];
    for (int i = tid; i < 512; i += 256) *(uint4*)(vz + i * 8) = z;
    dma_tile(0, &Ks[0][0], &Vt3[0][0]);
  }
  __syncthreads();   // full drain once (prologue only)

  int vw = 1, vr = 2;   // write slot for V(t+1); read slot holds V(t-1)
  for (int t = 0; t < NKT; ++t) {
    // drain own ds ops, then raw barrier (no vmcnt drain: DMAs stay in flight)
    asm volatile("s_waitcnt lgkmcnt(0)" ::: "memory");
    __builtin_amdgcn_s_barrier();

    const int kb = t & 1;
    if (t + 1 < NKT) {
      dma_tile(t + 1, &Ks[kb ^ 1][0], &Vt3[vw][0]);
      asm volatile("s_waitcnt vmcnt(24)" ::: "memory");   // tile t complete (own DMAs)
    } else {
      asm volatile("s_waitcnt vmcnt(0)" ::: "memory");
    }

    // ---- V(t-1) + P(t-1) frags ----
    short8 vf[8], paf[2][2];
    const unsigned short* vc = &Vt3[vr][0];
#pragma unroll
    for (int nt8 = 0; nt8 < 8; ++nt8)
      vf[nt8] = *(const short8*)&vc[nt8 * 512 + vro];
#pragma unroll
    for (int st = 0; st < 2; ++st)
#pragma unroll
      for (int mt = 0; mt < 2; ++mt)
        paf[st][mt] = *(const short8*)&Pa[wave][st][mt * 16 + l16][pa_rd_off];

    // ---- pipelined compute: QK(t) interleaved with PV(t-1) ----
    f32x4 sa0[2][2], sa1[2][2];
#pragma unroll
    for (int mt = 0; mt < 2; ++mt)
#pragma unroll
      for (int nt = 0; nt < 2; ++nt) {
        sa0[mt][nt] = (f32x4){0.f, 0.f, 0.f, 0.f};
        sa1[mt][nt] = (f32x4){0.f, 0.f, 0.f, 0.f};
      }
    qk(0, kb, sa0);
    pv(0, paf[0], vf);
    pexp(0, sa0);
    qk(1, kb, sa1);
    pv(1, paf[1], vf);
    pexp(1, sa1);

    vw = (vw == 2) ? 0 : vw + 1;
    vr = (vr == 2) ? 0 : vr + 1;
  }

  // ---- epilogue PV(NKT-1): V(63) is in slot vr (= 63%3 = 0 after rotation) ----
  {
    short8 paf[2][2], vf[8];
    const unsigned short* vc = &Vt3[vr][0];
#pragma unroll
    for (int nt8 = 0; nt8 < 8; ++nt8)
      vf[nt8] = *(const short8*)&vc[nt8 * 512 + vro];
#pragma unroll
    for (int st = 0; st < 2; ++st)
#pragma unroll
      for (int mt = 0; mt < 2; ++mt)
        paf[st][mt] = *(const short8*)&Pa[wave][st][mt * 16 + l16][pa_rd_off];
    pv(0, paf[0], vf);
    pv(1, paf[1], vf);
  }

  // ---- softmax denominators ----
#pragma unroll
  for (int mt = 0; mt < 2; ++mt)
#pragma unroll
    for (int st = 0; st < 2; ++st)
#pragma unroll
      for (int r = 0; r < 4; ++r) {
        float v = lacc[mt][st][r];
        v += __shfl_xor(v, 1, 16);
        v += __shfl_xor(v, 2, 16);
        v += __shfl_xor(v, 4, 16);
        v += __shfl_xor(v, 8, 16);
        lacc[mt][st][r] = v;
      }

  float sum = 0.f, ssq = 0.f;
#pragma unroll
  for (int mt = 0; mt < 2; ++mt) {
    float i1[4], i2[4];
#pragma unroll
    for (int r = 0; r < 4; ++r) {
      i1[r] = 1.f / lacc[mt][0][r];
      i2[r] = lam / lacc[mt][1][r];
    }
#pragma unroll
    for (int nt8 = 0; nt8 < 8; ++nt8)
#pragma unroll
      for (int r = 0; r < 4; ++r) {
        float o = acc[mt][0][nt8][r] * i1[r] - acc[mt][1][nt8][r] * i2[r];
        int row = q0 + wave * 32 + mt * 16 + quad * 4 + r;
        out[((size_t)bh * S + row) * D + nt8 * 16 + l16] = o;
        sum += o; ssq += o * o;
      }
  }
#pragma unroll
  for (int off = 32; off >= 1; off >>= 1) {
    sum += __shfl_xor(sum, off, 64);
    ssq += __shfl_xor(ssq, off, 64);
  }
  if (lane == 0) { sred[wave][0] = sum; sred[wave][1] = ssq; }
  __syncthreads();
  if (tid == 0) {
    float s0 = sred[0][0] + sred[1][0] + sred[2][0] + sred[3][0];
    float s1 = sred[0][1] + sred[1][1] + sred[2][1] + sred[3][1];
    int idx = bh * 16 + qb;
    wsf[64 + idx * 2] = s0;
    wsf[64 + idx * 2 + 1] = s1;
  }
}

// ---------------- kernel 2: group norm (in-place on out) ----------------
__global__ void gn_kernel(float* __restrict__ out, const float* __restrict__ gw,
                          const float* __restrict__ gb, const float* __restrict__ wsf) {
  const int bh = blockIdx.x, part = blockIdx.y;
  const int h = bh & (H - 1);
  float sum = 0.f, ssq = 0.f;
  for (int j = 0; j < 16; ++j) {
    sum += wsf[64 + (bh * 16 + j) * 2];
    ssq += wsf[64 + (bh * 16 + j) * 2 + 1];
  }
  const float invn = 1.f / (float)(S * D);
  const float mean = sum * invn;
  const float var = ssq * invn - mean * mean;
  const float rstd = rsqrtf(var + GN_EPS);
  const float outscale = 1.f - LAM_INIT;
  const float4* g4 = (const float4*)(gw + h * D);
  const float4* b4 = (const float4*)(gb + h * D);
  float4* o4 = (float4*)(out + (size_t)bh * S * D);
  const int chunks_per = (S * D / 4) / 32;   // 2048
  const int c0 = part * chunks_per;
  for (int c = c0 + threadIdx.x; c < c0 + chunks_per; c += 256) {
    float4 vv = o4[c];
    int d4 = c & 31;
    float4 g = g4[d4], bb = b4[d4];
    vv.x = ((vv.x - mean) * rstd * g.x + bb.x) * outscale;
    vv.y = ((vv.y - mean) * rstd * g.y + bb.y) * outscale;
    vv.z = ((vv.z - mean) * rstd * g.z + bb.z) * outscale;
    vv.w = ((vv.w - mean) * rstd * g.w + bb.w) * outscale;
    o4[c] = vv;
  }
}

extern "C" void kernel_launch(void* const* d_in, const int* in_sizes, int n_in,
                              void* d_out, int out_size, void* d_ws, size_t ws_size,
                              hipStream_t stream) {
  (void)in_sizes; (void)n_in; (void)out_size; (void)ws_size;
  const float* q   = (const float*)d_in[0];
  const float* k   = (const float*)d_in[1];
  const float* v   = (const float*)d_in[2];
  const float* lq1 = (const float*)d_in[3];
  const float* lq2 = (const float*)d_in[4];
  const float* lk1 = (const float*)d_in[5];
  const float* lk2 = (const float*)d_in[6];
  const float* gw  = (const float*)d_in[7];
  const float* gb  = (const float*)d_in[8];
  float* out = (float*)d_out;
  float* wsf = (float*)d_ws;
  unsigned short* vtg = (unsigned short*)((char*)d_ws + 8192);
  unsigned short* kbf = (unsigned short*)((char*)d_ws + 8192 + (size_t)BH * D * S * 2);

  prep_kernel<<<dim3(S / 64, BH), dim3(256), 0, stream>>>(k, v, lq1, lq2, lk1, lk2, kbf, vtg, wsf);
  attn_kernel<<<dim3(BH, S / QTILE), dim3(256), 0, stream>>>(q, kbf, vtg, wsf, out);
  gn_kernel<<<dim3(BH, 32), dim3(256), 0, stream>>>(out, gw, gb, wsf);
}

// Round 6
// 433.716 us; speedup vs baseline: 1.4242x; 1.0501x over previous
//
#include <hip/hip_runtime.h>
#include <cstddef>

constexpr int B = 2, H = 16, S = 2048, D = 128;
constexpr int BH = B * H;
constexpr int TWOD = 2 * D;          // 256
constexpr int QTILE = 128;           // q rows per block: 4 waves x 2 mtiles x 16
constexpr int BC = 32;               // keys per tile
constexpr int NKT = S / BC;          // 64
constexpr float SC2 = 0.08838834764831845f * 1.4426950408889634f; // (1/sqrt(128))*log2(e)
constexpr float LAM_INIT = 0.8f;
constexpr float GN_EPS = 1e-5f;

typedef __attribute__((ext_vector_type(8))) short short8;
typedef __attribute__((ext_vector_type(4))) float f32x4;

__device__ __forceinline__ unsigned short f2b(float f) {
  unsigned int u = __float_as_uint(f);
  u += 0x7fffu + ((u >> 16) & 1u);
  return (unsigned short)(u >> 16);
}

__device__ __forceinline__ void async_copy16(const void* g, void* l) {
  typedef __attribute__((address_space(1))) const void gvoid;
  typedef __attribute__((address_space(3))) void lvoid;
  __builtin_amdgcn_global_load_lds((gvoid*)g, (lvoid*)l, 16, 0, 0);
}

// ---------------- kernel 0: fused prep (lam + K bf16 + V^T bf16) ----------------
// grid (S/128, BH): 128-row tiles -> 256B-contiguous vtg write segments.
__global__ void prep_kernel(const float* __restrict__ k, const float* __restrict__ v,
                            const float* __restrict__ lq1, const float* __restrict__ lq2,
                            const float* __restrict__ lk1, const float* __restrict__ lk2,
                            unsigned short* __restrict__ kbf, unsigned short* __restrict__ vtg,
                            float* __restrict__ wsf) {
  __shared__ float tile[128][129];
  const int bh = blockIdx.y, s0 = blockIdx.x * 128, t = threadIdx.x;

  if (blockIdx.x == 0 && blockIdx.y == 0) {
    if (t < 128) {
      tile[0][t] = lq1[t] * lk1[t];
      tile[1][t] = lq2[t] * lk2[t];
    }
    __syncthreads();
    if (t == 0) {
      float s1 = 0.f, s2 = 0.f;
      for (int i = 0; i < 128; ++i) { s1 += tile[0][i]; s2 += tile[1][i]; }
      wsf[0] = expf(s1) - expf(s2) + LAM_INIT;
    }
    __syncthreads();
  }

  // K convert: 128 rows x 256 cols fp32 -> bf16, contiguous
  {
    const float* ks = k + ((size_t)bh * S + s0) * TWOD;
    unsigned short* kd = kbf + ((size_t)bh * S + s0) * TWOD;
#pragma unroll
    for (int i = 0; i < 16; ++i) {
      size_t off = (size_t)(i * 256 + t) * 8;
      float4 a = *(const float4*)(ks + off);
      float4 b2 = *(const float4*)(ks + off + 4);
      unsigned short u[8];
      u[0] = f2b(a.x); u[1] = f2b(a.y); u[2] = f2b(a.z); u[3] = f2b(a.w);
      u[4] = f2b(b2.x); u[5] = f2b(b2.y); u[6] = f2b(b2.z); u[7] = f2b(b2.w);
      *(uint4*)(kd + off) = *(uint4*)u;
    }
  }

  // V transpose: 128s x 128d -> [d][s]
#pragma unroll
  for (int i = 0; i < 16; ++i) {
    int idx = t + i * 256;            // 4096 f4 chunks (128 s x 32 f4)
    int row = idx >> 5, c4 = idx & 31;
    float4 f = *(const float4*)(v + ((size_t)bh * S + s0 + row) * D + c4 * 4);
    tile[row][c4 * 4 + 0] = f.x; tile[row][c4 * 4 + 1] = f.y;
    tile[row][c4 * 4 + 2] = f.z; tile[row][c4 * 4 + 3] = f.w;
  }
  __syncthreads();
#pragma unroll
  for (int i = 0; i < 8; ++i) {
    int c = t + i * 256;              // 2048 chunks (128 d x 16 k-groups)
    int d = c >> 4, k8 = c & 15;
    unsigned short u[8];
#pragma unroll
    for (int j = 0; j < 8; ++j) u[j] = f2b(tile[k8 * 8 + j][d]);
    *(uint4*)(vtg + ((size_t)bh * D + d) * S + s0 + k8 * 8) = *(uint4*)u;
  }
}

// ---------------- kernel 1: flash attention, partitioned drain-free K-loop ----------------
// Each wave DMAs 1/4 of the K and V tile (6 global_load_lds_dwordx4 per tile).
// In-order vmcnt completion: after issuing dma(t+1), s_waitcnt vmcnt(6) proves
// MY dma(t) landed; barrier2 proves EVERYONE's did. barrier1 (lgkmcnt only)
// fences buffer reuse. vmcnt never drains to 0 mid-loop: tile t+1's loads stay
// in flight across both barriers. PV(t-1) overlaps QK(t); Pa wave-private.
__global__ __launch_bounds__(256, 2)
void attn_kernel(const float* __restrict__ q, const unsigned short* __restrict__ kbf,
                 const unsigned short* __restrict__ vtg,
                 float* __restrict__ wsf, float* __restrict__ out) {
  __shared__ __attribute__((aligned(16))) unsigned short Ks[2][8192];   // 32 keys x 256, chunk-swizzled
  __shared__ __attribute__((aligned(16))) unsigned short Vt3[3][4096];  // 128 d x 32 keys, chunk-swizzled
  __shared__ __attribute__((aligned(16))) unsigned short Pa[4][2][32][40];
  __shared__ float sred[4][2];

  const int bh = blockIdx.x, qb = blockIdx.y;
  const int q0 = qb * QTILE;
  const int tid = threadIdx.x;
  const int wave = tid >> 6, lane = tid & 63;
  const int quad = lane >> 4, l16 = lane & 15;

  // load lambda early and pin it (keep it out of the loop's vmcnt window)
  const float lam = wsf[0];
  asm volatile("" :: "v"(lam));

  // ---- register-resident bf16 Q fragments (A-layout) ----
  short8 qf[2][2][4];                 // [mtile][stream][kstep]
#pragma unroll
  for (int mt = 0; mt < 2; ++mt) {
    int qrow = q0 + wave * 32 + mt * 16 + l16;
    const float* qr = q + ((size_t)bh * S + qrow) * TWOD;
#pragma unroll
    for (int st = 0; st < 2; ++st)
#pragma unroll
      for (int ks = 0; ks < 4; ++ks) {
        const float* p = qr + st * D + ks * 32 + quad * 8;
        float4 f0 = *(const float4*)p;
        float4 f1 = *(const float4*)(p + 4);
        short8 v8;
        v8[0] = (short)f2b(f0.x); v8[1] = (short)f2b(f0.y);
        v8[2] = (short)f2b(f0.z); v8[3] = (short)f2b(f0.w);
        v8[4] = (short)f2b(f1.x); v8[5] = (short)f2b(f1.y);
        v8[6] = (short)f2b(f1.z); v8[7] = (short)f2b(f1.w);
        qf[mt][st][ks] = v8;
      }
  }

  // ---- per-wave partitioned DMA offsets ----
  // K: wave handles chunks [wave*256, wave*256+256): instr i, chunk = wave*256+i*64+lane
  //    row = chunk>>5 = wave*8+i*2+(lane>>5); cs = lane&31; src chunk = cs^(row&7)
  int ksrc[4], kdst[4];
#pragma unroll
  for (int i = 0; i < 4; ++i) {
    int chunk = wave * 256 + i * 64 + lane;
    int row = chunk >> 5, cs = lane & 31;
    ksrc[i] = row * 256 + (cs ^ (row & 7)) * 8;
    kdst[i] = chunk * 8;
  }
  // V: wave handles chunks [wave*128, +128): chunk = wave*128+i*64+lane
  //    d = chunk>>2; cs = lane&3; src chunk = cs^(d&3)
  int vsrc[2], vdst[2];
#pragma unroll
  for (int i = 0; i < 2; ++i) {
    int chunk = wave * 128 + i * 64 + lane;
    int d = chunk >> 2, cs = lane & 3;
    vsrc[i] = d * S + (cs ^ (d & 3)) * 8;
    vdst[i] = chunk * 8;
  }
  const unsigned short* kbase = kbf + (size_t)bh * S * (size_t)TWOD;
  const unsigned short* vbase = vtg + (size_t)bh * D * (size_t)S;

  f32x4 acc[2][2][8];
#pragma unroll
  for (int mt = 0; mt < 2; ++mt)
#pragma unroll
    for (int st = 0; st < 2; ++st)
#pragma unroll
      for (int n = 0; n < 8; ++n) acc[mt][st][n] = (f32x4){0.f, 0.f, 0.f, 0.f};
  float lacc[2][2][4];
#pragma unroll
  for (int mt = 0; mt < 2; ++mt)
#pragma unroll
    for (int st = 0; st < 2; ++st)
#pragma unroll
      for (int r = 0; r < 4; ++r) lacc[mt][st][r] = 0.f;

  const int pa_rd_off = (quad ^ ((l16 >> 2) & 3)) * 8;
  const int vro = l16 * 32 + ((quad ^ (l16 & 3)) * 8);

  auto qk = [&](int st, int kb, f32x4 (&sa)[2][2]) {
#pragma unroll
    for (int nt = 0; nt < 2; ++nt) {
      const int row = nt * 16 + l16;
      const int rx = row & 7;
#pragma unroll
      for (int ks = 0; ks < 4; ++ks) {
        const int pos = (st * 16 + ks * 4 + quad) ^ rx;
        const short8 kf = *(const short8*)&Ks[kb][row * 256 + pos * 8];
        sa[0][nt] = __builtin_amdgcn_mfma_f32_16x16x32_bf16(qf[0][st][ks], kf, sa[0][nt], 0, 0, 0);
        sa[1][nt] = __builtin_amdgcn_mfma_f32_16x16x32_bf16(qf[1][st][ks], kf, sa[1][nt], 0, 0, 0);
      }
    }
  };
  auto pexp = [&](int st, f32x4 (&sa)[2][2]) {
#pragma unroll
    for (int mt = 0; mt < 2; ++mt)
#pragma unroll
      for (int nt = 0; nt < 2; ++nt)
#pragma unroll
        for (int r = 0; r < 4; ++r) {
          float p = __builtin_amdgcn_exp2f(sa[mt][nt][r] * SC2);
          lacc[mt][st][r] += p;
          int colp = (((nt * 2) + (l16 >> 3)) ^ quad) * 8 + (l16 & 7);
          Pa[wave][st][mt * 16 + quad * 4 + r][colp] = f2b(p);
        }
  };
  auto pv = [&](int st, const short8 (&paf)[2], const short8 (&vf)[8]) {
#pragma unroll
    for (int nt8 = 0; nt8 < 8; ++nt8)
#pragma unroll
      for (int mt = 0; mt < 2; ++mt)
        acc[mt][st][nt8] = __builtin_amdgcn_mfma_f32_16x16x32_bf16(paf[mt], vf[nt8], acc[mt][st][nt8], 0, 0, 0);
  };
  auto dma_tile = [&](int t, unsigned short* kd, unsigned short* vd) {
    const unsigned short* kp = kbase + (size_t)t * BC * TWOD;
#pragma unroll
    for (int i = 0; i < 4; ++i)
      async_copy16(kp + ksrc[i], kd + kdst[i]);
    const unsigned short* vp = vbase + t * BC;
#pragma unroll
    for (int i = 0; i < 2; ++i)
      async_copy16(vp + vsrc[i], vd + vdst[i]);
  };

  // ---- prologue: zero Pa + V slot 2 (PV(-1) multiplies exact zeros), DMA tile 0 ----
  {
    const uint4 z = {0u, 0u, 0u, 0u};
    unsigned short* pz = &Pa[0][0][0][0];
    for (int i = tid; i < 1280; i += 256) *(uint4*)(pz + i * 8) = z;
    unsigned short* vz = &Vt3[2][0];
    for (int i = tid; i < 512; i += 256) *(uint4*)(vz + i * 8) = z;
    dma_tile(0, &Ks[0][0], &Vt3[0][0]);
  }

  for (int t = 0; t < NKT; ++t) {
    // barrier1: my ds ops (frag reads + Pa writes of t-1; prologue zeros at t=0)
    // done; all waves past compute(t-1) -> safe to overwrite Ks[(t+1)&1], Vslot[(t+1)%3]
    asm volatile("s_waitcnt lgkmcnt(0)" ::: "memory");
    __builtin_amdgcn_s_barrier();

    if (t + 1 < NKT) {
      dma_tile(t + 1, &Ks[(t + 1) & 1][0], &Vt3[(t + 1) % 3][0]);
      asm volatile("s_waitcnt vmcnt(6)" ::: "memory");   // my dma(t) landed (in-order)
    } else {
      asm volatile("s_waitcnt vmcnt(0)" ::: "memory");
    }
    __builtin_amdgcn_s_barrier();    // barrier2: everyone's dma(t) landed

    // ---- V(t-1) + P(t-1) frags ----
    short8 vf[8], paf[2][2];
    const unsigned short* vc = &Vt3[(t + 2) % 3][0];     // (t-1) mod 3
#pragma unroll
    for (int nt8 = 0; nt8 < 8; ++nt8)
      vf[nt8] = *(const short8*)&vc[nt8 * 512 + vro];
#pragma unroll
    for (int st = 0; st < 2; ++st)
#pragma unroll
      for (int mt = 0; mt < 2; ++mt)
        paf[st][mt] = *(const short8*)&Pa[wave][st][mt * 16 + l16][pa_rd_off];

    // ---- pipelined compute: QK(t) interleaved with PV(t-1) ----
    f32x4 sa0[2][2], sa1[2][2];
#pragma unroll
    for (int mt = 0; mt < 2; ++mt)
#pragma unroll
      for (int nt = 0; nt < 2; ++nt) {
        sa0[mt][nt] = (f32x4){0.f, 0.f, 0.f, 0.f};
        sa1[mt][nt] = (f32x4){0.f, 0.f, 0.f, 0.f};
      }
    const int kb = t & 1;
    qk(0, kb, sa0);
    pv(0, paf[0], vf);
    pexp(0, sa0);
    qk(1, kb, sa1);
    pv(1, paf[1], vf);
    pexp(1, sa1);
  }

  // ---- epilogue PV(NKT-1): V(63) in slot 63%3 = 0 ----
  {
    short8 paf[2][2], vf[8];
    const unsigned short* vc = &Vt3[(NKT - 1) % 3][0];
#pragma unroll
    for (int nt8 = 0; nt8 < 8; ++nt8)
      vf[nt8] = *(const short8*)&vc[nt8 * 512 + vro];
#pragma unroll
    for (int st = 0; st < 2; ++st)
#pragma unroll
      for (int mt = 0; mt < 2; ++mt)
        paf[st][mt] = *(const short8*)&Pa[wave][st][mt * 16 + l16][pa_rd_off];
    pv(0, paf[0], vf);
    pv(1, paf[1], vf);
  }

  // ---- softmax denominators ----
#pragma unroll
  for (int mt = 0; mt < 2; ++mt)
#pragma unroll
    for (int st = 0; st < 2; ++st)
#pragma unroll
      for (int r = 0; r < 4; ++r) {
        float v = lacc[mt][st][r];
        v += __shfl_xor(v, 1, 16);
        v += __shfl_xor(v, 2, 16);
        v += __shfl_xor(v, 4, 16);
        v += __shfl_xor(v, 8, 16);
        lacc[mt][st][r] = v;
      }

  float sum = 0.f, ssq = 0.f;
#pragma unroll
  for (int mt = 0; mt < 2; ++mt) {
    float i1[4], i2[4];
#pragma unroll
    for (int r = 0; r < 4; ++r) {
      i1[r] = 1.f / lacc[mt][0][r];
      i2[r] = lam / lacc[mt][1][r];
    }
#pragma unroll
    for (int nt8 = 0; nt8 < 8; ++nt8)
#pragma unroll
      for (int r = 0; r < 4; ++r) {
        float o = acc[mt][0][nt8][r] * i1[r] - acc[mt][1][nt8][r] * i2[r];
        int row = q0 + wave * 32 + mt * 16 + quad * 4 + r;
        out[((size_t)bh * S + row) * D + nt8 * 16 + l16] = o;
        sum += o; ssq += o * o;
      }
  }
#pragma unroll
  for (int off = 32; off >= 1; off >>= 1) {
    sum += __shfl_xor(sum, off, 64);
    ssq += __shfl_xor(ssq, off, 64);
  }
  if (lane == 0) { sred[wave][0] = sum; sred[wave][1] = ssq; }
  __syncthreads();
  if (tid == 0) {
    float s0 = sred[0][0] + sred[1][0] + sred[2][0] + sred[3][0];
    float s1 = sred[0][1] + sred[1][1] + sred[2][1] + sred[3][1];
    int idx = bh * 16 + qb;
    wsf[64 + idx * 2] = s0;
    wsf[64 + idx * 2 + 1] = s1;
  }
}

// ---------------- kernel 2: group norm (in-place on out) ----------------
__global__ void gn_kernel(float* __restrict__ out, const float* __restrict__ gw,
                          const float* __restrict__ gb, const float* __restrict__ wsf) {
  const int bh = blockIdx.x, part = blockIdx.y;
  const int h = bh & (H - 1);
  float sum = 0.f, ssq = 0.f;
  for (int j = 0; j < 16; ++j) {
    sum += wsf[64 + (bh * 16 + j) * 2];
    ssq += wsf[64 + (bh * 16 + j) * 2 + 1];
  }
  const float invn = 1.f / (float)(S * D);
  const float mean = sum * invn;
  const float var = ssq * invn - mean * mean;
  const float rstd = rsqrtf(var + GN_EPS);
  const float outscale = 1.f - LAM_INIT;
  const float4* g4 = (const float4*)(gw + h * D);
  const float4* b4 = (const float4*)(gb + h * D);
  float4* o4 = (float4*)(out + (size_t)bh * S * D);
  const int chunks_per = (S * D / 4) / 32;   // 2048
  const int c0 = part * chunks_per;
  for (int c = c0 + threadIdx.x; c < c0 + chunks_per; c += 256) {
    float4 vv = o4[c];
    int d4 = c & 31;
    float4 g = g4[d4], bb = b4[d4];
    vv.x = ((vv.x - mean) * rstd * g.x + bb.x) * outscale;
    vv.y = ((vv.y - mean) * rstd * g.y + bb.y) * outscale;
    vv.z = ((vv.z - mean) * rstd * g.z + bb.z) * outscale;
    vv.w = ((vv.w - mean) * rstd * g.w + bb.w) * outscale;
    o4[c] = vv;
  }
}

extern "C" void kernel_launch(void* const* d_in, const int* in_sizes, int n_in,
                              void* d_out, int out_size, void* d_ws, size_t ws_size,
                              hipStream_t stream) {
  (void)in_sizes; (void)n_in; (void)out_size; (void)ws_size;
  const float* q   = (const float*)d_in[0];
  const float* k   = (const float*)d_in[1];
  const float* v   = (const float*)d_in[2];
  const float* lq1 = (const float*)d_in[3];
  const float* lq2 = (const float*)d_in[4];
  const float* lk1 = (const float*)d_in[5];
  const float* lk2 = (const float*)d_in[6];
  const float* gw  = (const float*)d_in[7];
  const float* gb  = (const float*)d_in[8];
  float* out = (float*)d_out;
  float* wsf = (float*)d_ws;
  unsigned short* vtg = (unsigned short*)((char*)d_ws + 8192);
  unsigned short* kbf = (unsigned short*)((char*)d_ws + 8192 + (size_t)BH * D * S * 2);

  prep_kernel<<<dim3(S / 128, BH), dim3(256), 0, stream>>>(k, v, lq1, lq2, lk1, lk2, kbf, vtg, wsf);
  attn_kernel<<<dim3(BH, S / QTILE), dim3(256), 0, stream>>>(q, kbf, vtg, wsf, out);
  gn_kernel<<<dim3(BH, 32), dim3(256), 0, stream>>>(out, gw, gb, wsf);
}

// Round 8
// 411.146 us; speedup vs baseline: 1.5024x; 1.0549x over previous
//
#include <hip/hip_runtime.h>
#include <cstddef>

constexpr int B = 2, H = 16, S = 2048, D = 128;
constexpr int BH = B * H;
constexpr int TWOD = 2 * D;          // 256
constexpr int QTILE = 128;           // q rows per block (waves 0-1: stream0, waves 2-3: stream1)
constexpr int BC = 32;               // keys per tile
constexpr int NKT = S / BC;          // 64
constexpr float SC2 = 0.08838834764831845f * 1.4426950408889634f; // (1/sqrt(128))*log2(e)
constexpr float LAM_INIT = 0.8f;
constexpr float GN_EPS = 1e-5f;

typedef __attribute__((ext_vector_type(8))) short short8;
typedef __attribute__((ext_vector_type(4))) float f32x4;

__device__ __forceinline__ unsigned short f2b(float f) {
  unsigned int u = __float_as_uint(f);
  u += 0x7fffu + ((u >> 16) & 1u);
  return (unsigned short)(u >> 16);
}

__device__ __forceinline__ unsigned int f2b_pk(float a, float b) {
  return (unsigned int)f2b(a) | ((unsigned int)f2b(b) << 16);
}

__device__ __forceinline__ void async_copy16(const void* g, void* l) {
  typedef __attribute__((address_space(1))) const void gvoid;
  typedef __attribute__((address_space(3))) void lvoid;
  __builtin_amdgcn_global_load_lds((gvoid*)g, (lvoid*)l, 16, 0, 0);
}

// ---------------- kernel 0: fused prep (lam + K bf16 + V^T bf16) ----------------
__global__ void prep_kernel(const float* __restrict__ k, const float* __restrict__ v,
                            const float* __restrict__ lq1, const float* __restrict__ lq2,
                            const float* __restrict__ lk1, const float* __restrict__ lk2,
                            unsigned short* __restrict__ kbf, unsigned short* __restrict__ vtg,
                            float* __restrict__ wsf) {
  __shared__ float tile[128][129];
  const int bh = blockIdx.y, s0 = blockIdx.x * 128, t = threadIdx.x;

  if (blockIdx.x == 0 && blockIdx.y == 0) {
    if (t < 128) {
      tile[0][t] = lq1[t] * lk1[t];
      tile[1][t] = lq2[t] * lk2[t];
    }
    __syncthreads();
    if (t == 0) {
      float s1 = 0.f, s2 = 0.f;
      for (int i = 0; i < 128; ++i) { s1 += tile[0][i]; s2 += tile[1][i]; }
      wsf[0] = expf(s1) - expf(s2) + LAM_INIT;
    }
    __syncthreads();
  }

  {
    const float* ks = k + ((size_t)bh * S + s0) * TWOD;
    unsigned short* kd = kbf + ((size_t)bh * S + s0) * TWOD;
#pragma unroll
    for (int i = 0; i < 16; ++i) {
      size_t off = (size_t)(i * 256 + t) * 8;
      float4 a = *(const float4*)(ks + off);
      float4 b2 = *(const float4*)(ks + off + 4);
      unsigned short u[8];
      u[0] = f2b(a.x); u[1] = f2b(a.y); u[2] = f2b(a.z); u[3] = f2b(a.w);
      u[4] = f2b(b2.x); u[5] = f2b(b2.y); u[6] = f2b(b2.z); u[7] = f2b(b2.w);
      *(uint4*)(kd + off) = *(uint4*)u;
    }
  }

#pragma unroll
  for (int i = 0; i < 16; ++i) {
    int idx = t + i * 256;
    int row = idx >> 5, c4 = idx & 31;
    float4 f = *(const float4*)(v + ((size_t)bh * S + s0 + row) * D + c4 * 4);
    tile[row][c4 * 4 + 0] = f.x; tile[row][c4 * 4 + 1] = f.y;
    tile[row][c4 * 4 + 2] = f.z; tile[row][c4 * 4 + 3] = f.w;
  }
  __syncthreads();
#pragma unroll
  for (int i = 0; i < 8; ++i) {
    int c = t + i * 256;
    int d = c >> 4, k8 = c & 15;
    unsigned short u[8];
#pragma unroll
    for (int j = 0; j < 8; ++j) u[j] = f2b(tile[k8 * 8 + j][d]);
    *(uint4*)(vtg + ((size_t)bh * D + d) * S + s0 + k8 * 8) = *(uint4*)u;
  }
}

// ---------------- kernel 1: flash attention, stream-split waves ----------------
// R3 structure (single __syncthreads per iter, K via DMA double-buffer, V via
// global->reg->LDS). Waves 0-1: stream 0 for q-rows [0,64)/[64,128); waves 2-3:
// stream 1, same rows. Each wave reads only its stream's K half (kf LDS traffic
// halved; ks-outer loop keeps only 2 kf frags live). Epilogue: stream-1 waves
// stage lam*O2/l2 (bf16) in the retired Ks LDS; stream-0 waves subtract, write
// out, and emit GN partials.
__global__ __launch_bounds__(256, 2)
void attn_kernel(const float* __restrict__ q, const unsigned short* __restrict__ kbf,
                 const unsigned short* __restrict__ vtg,
                 float* __restrict__ wsf, float* __restrict__ out) {
  __shared__ __attribute__((aligned(16))) unsigned short Ks[2][32][256];  // 32 KB, chunk-swizzled
  __shared__ __attribute__((aligned(16))) unsigned short Vt[2][128][40];  // 20 KB
  __shared__ __attribute__((aligned(16))) unsigned short Pa[4][64][40];   // 20.5 KB wave-private P
  __shared__ float sred[2][2];

  const int bh = blockIdx.x, qb = blockIdx.y;
  const int q0 = qb * QTILE;
  const int tid = threadIdx.x;
  const int wave = tid >> 6, lane = tid & 63;
  const int quad = lane >> 4, l16 = lane & 15;
  const int st = wave >> 1;          // this wave's stream
  const int qh = wave & 1;           // q-half
  const float lam = wsf[0];

  // ---- register-resident bf16 Q fragments (A-layout), this wave's stream only ----
  short8 qf[4][4];                    // [mtile][kstep]
#pragma unroll
  for (int mt = 0; mt < 4; ++mt) {
    int qrow = q0 + qh * 64 + mt * 16 + l16;
    const float* qr = q + ((size_t)bh * S + qrow) * TWOD + st * D;
#pragma unroll
    for (int ks = 0; ks < 4; ++ks) {
      const float* p = qr + ks * 32 + quad * 8;
      float4 f0 = *(const float4*)p;
      float4 f1 = *(const float4*)(p + 4);
      short8 v8;
      v8[0] = (short)f2b(f0.x); v8[1] = (short)f2b(f0.y);
      v8[2] = (short)f2b(f0.z); v8[3] = (short)f2b(f0.w);
      v8[4] = (short)f2b(f1.x); v8[5] = (short)f2b(f1.y);
      v8[6] = (short)f2b(f1.z); v8[7] = (short)f2b(f1.w);
      qf[mt][ks] = v8;
    }
  }

  // ---- staging addresses (block-partitioned, as R3) ----
  const unsigned short* kbase = kbf + (size_t)bh * S * (size_t)TWOD;
  int goff[4];
#pragma unroll
  for (int i = 0; i < 4; ++i) {
    int L = i * 256 + tid;
    int row = L >> 5, cp = L & 31;
    goff[i] = row * 256 + (cp ^ (row & 7)) * 8;
  }
  const unsigned short* vbase = vtg + (size_t)bh * D * (size_t)S;
  const int vd0 = tid >> 2, vcp = tid & 3;

  f32x4 acc[4][8];                    // [mtile][d-tile], this stream only
#pragma unroll
  for (int mt = 0; mt < 4; ++mt)
#pragma unroll
    for (int n = 0; n < 8; ++n) acc[mt][n] = (f32x4){0.f, 0.f, 0.f, 0.f};
  float lacc[4][4];
#pragma unroll
  for (int mt = 0; mt < 4; ++mt)
#pragma unroll
    for (int r = 0; r < 4; ++r) lacc[mt][r] = 0.f;

  const int pa_rd_off = (quad ^ ((l16 >> 2) & 3)) * 8;
  const int colp0 = ((0 + (l16 >> 3)) ^ quad) * 8 + (l16 & 7);
  const int colp1 = ((2 + (l16 >> 3)) ^ quad) * 8 + (l16 & 7);

  // ---- prologue: zero Pa + Vt[1], stage tile 0 ----
  {
    const uint4 z = {0u, 0u, 0u, 0u};
    unsigned short* pz = &Pa[0][0][0];
    for (int i = tid; i < 1280; i += 256) *(uint4*)(pz + i * 8) = z;
    unsigned short* vz = &Vt[1][0][0];
    for (int i = tid; i < 640; i += 256) *(uint4*)(vz + i * 8) = z;
#pragma unroll
    for (int i = 0; i < 4; ++i)
      async_copy16(kbase + goff[i], &Ks[0][0][0] + (i * 256 + tid) * 8);
    uint4 v0 = *(const uint4*)(vbase + (size_t)vd0 * S + vcp * 8);
    uint4 v1 = *(const uint4*)(vbase + (size_t)(vd0 + 64) * S + vcp * 8);
    *(uint4*)&Vt[0][vd0][vcp * 8] = v0;
    *(uint4*)&Vt[0][vd0 + 64][vcp * 8] = v1;
  }
  __syncthreads();

  for (int t = 0; t < NKT; ++t) {
    const int kb = t & 1;
    const int pvbuf = kb ^ 1;        // holds V(t-1); target for K(t+1)/V(t+1)

    // ---- top-of-iter LDS reads: P(t-1) A-frags + V(t-1) B-frags ----
    short8 paf[4], vf[8];
#pragma unroll
    for (int mt = 0; mt < 4; ++mt)
      paf[mt] = *(const short8*)&Pa[wave][mt * 16 + l16][pa_rd_off];
#pragma unroll
    for (int nt8 = 0; nt8 < 8; ++nt8)
      vf[nt8] = *(const short8*)&Vt[pvbuf][nt8 * 16 + l16][quad * 8];

    // ---- prefetch tile t+1 ----
    const bool pre = (t + 1 < NKT);
    uint4 vr0, vr1;
    if (pre) {
      const unsigned short* vp = vbase + (t + 1) * BC + vcp * 8;
      vr0 = *(const uint4*)(vp + (size_t)vd0 * S);
      vr1 = *(const uint4*)(vp + (size_t)(vd0 + 64) * S);
      const unsigned short* kp = kbase + (size_t)(t + 1) * BC * TWOD;
      unsigned short* ldsb = &Ks[pvbuf][0][0];
#pragma unroll
      for (int i = 0; i < 4; ++i)
        async_copy16(kp + goff[i], ldsb + (i * 256 + tid) * 8);
    }

    // ---- QK(t): ks-outer so only 2 kf frags live; 8 independent MFMA chains ----
    f32x4 sa[4][2];
#pragma unroll
    for (int mt = 0; mt < 4; ++mt)
#pragma unroll
      for (int nt = 0; nt < 2; ++nt) sa[mt][nt] = (f32x4){0.f, 0.f, 0.f, 0.f};
#pragma unroll
    for (int ks = 0; ks < 4; ++ks)
#pragma unroll
      for (int nt = 0; nt < 2; ++nt) {
        const int row = nt * 16 + l16;
        const int pos = (st * 16 + ks * 4 + quad) ^ (row & 7);
        const short8 kf = *(const short8*)&Ks[kb][row][pos * 8];
#pragma unroll
        for (int mt = 0; mt < 4; ++mt)
          sa[mt][nt] = __builtin_amdgcn_mfma_f32_16x16x32_bf16(qf[mt][ks], kf, sa[mt][nt], 0, 0, 0);
      }

    // ---- PV(t-1): independent of QK(t), fills its latency shadow ----
#pragma unroll
    for (int nt8 = 0; nt8 < 8; ++nt8)
#pragma unroll
      for (int mt = 0; mt < 4; ++mt)
        acc[mt][nt8] = __builtin_amdgcn_mfma_f32_16x16x32_bf16(paf[mt], vf[nt8], acc[mt][nt8], 0, 0, 0);

    // ---- exp + packed-bf16 P write to wave-private LDS ----
#pragma unroll
    for (int mt = 0; mt < 4; ++mt)
#pragma unroll
      for (int nt = 0; nt < 2; ++nt) {
        float p0 = __builtin_amdgcn_exp2f(sa[mt][nt][0] * SC2);
        float p1 = __builtin_amdgcn_exp2f(sa[mt][nt][1] * SC2);
        float p2 = __builtin_amdgcn_exp2f(sa[mt][nt][2] * SC2);
        float p3 = __builtin_amdgcn_exp2f(sa[mt][nt][3] * SC2);
        lacc[mt][0] += p0; lacc[mt][1] += p1;
        lacc[mt][2] += p2; lacc[mt][3] += p3;
        unsigned int u01 = f2b_pk(p0, p1);
        unsigned int u23 = f2b_pk(p2, p3);
        const int colp = nt ? colp1 : colp0;
        const int rbase = mt * 16 + quad * 4;
        Pa[wave][rbase + 0][colp] = (unsigned short)u01;
        Pa[wave][rbase + 1][colp] = (unsigned short)(u01 >> 16);
        Pa[wave][rbase + 2][colp] = (unsigned short)u23;
        Pa[wave][rbase + 3][colp] = (unsigned short)(u23 >> 16);
      }

    __syncthreads();                 // drains K(t+1) DMA; fences Ks/Vt reuse
    if (pre) {
      *(uint4*)&Vt[pvbuf][vd0][vcp * 8] = vr0;
      *(uint4*)&Vt[pvbuf][vd0 + 64][vcp * 8] = vr1;
    }
  }

  // ---- epilogue PV(NKT-1): V(63) stored into Vt[1] during t=62 ----
  {
    short8 paf[4], vf[8];
#pragma unroll
    for (int mt = 0; mt < 4; ++mt)
      paf[mt] = *(const short8*)&Pa[wave][mt * 16 + l16][pa_rd_off];
#pragma unroll
    for (int nt8 = 0; nt8 < 8; ++nt8)
      vf[nt8] = *(const short8*)&Vt[1][nt8 * 16 + l16][quad * 8];
#pragma unroll
    for (int nt8 = 0; nt8 < 8; ++nt8)
#pragma unroll
      for (int mt = 0; mt < 4; ++mt)
        acc[mt][nt8] = __builtin_amdgcn_mfma_f32_16x16x32_bf16(paf[mt], vf[nt8], acc[mt][nt8], 0, 0, 0);
  }

  // ---- softmax denominators (reduce across the 16-lane row groups) ----
#pragma unroll
  for (int mt = 0; mt < 4; ++mt)
#pragma unroll
    for (int r = 0; r < 4; ++r) {
      float v = lacc[mt][r];
      v += __shfl_xor(v, 1, 16);
      v += __shfl_xor(v, 2, 16);
      v += __shfl_xor(v, 4, 16);
      v += __shfl_xor(v, 8, 16);
      lacc[mt][r] = v;
    }

  __syncthreads();   // all kf reads of Ks done -> safe to reuse Ks as O2 buffer
  unsigned short* O2 = &Ks[0][0][0];         // [128 q][128 d] bf16 = 32 KB exactly

  if (st == 1) {     // stream-1 waves: stage lam * O2 / l2 as bf16
#pragma unroll
    for (int mt = 0; mt < 4; ++mt) {
      float i2[4];
#pragma unroll
      for (int r = 0; r < 4; ++r) i2[r] = lam / lacc[mt][r];
#pragma unroll
      for (int nt8 = 0; nt8 < 8; ++nt8)
#pragma unroll
        for (int r = 0; r < 4; ++r) {
          int row = qh * 64 + mt * 16 + quad * 4 + r;
          O2[row * 128 + nt8 * 16 + l16] = f2b(acc[mt][nt8][r] * i2[r]);
        }
    }
  }
  __syncthreads();

  float sum = 0.f, ssq = 0.f;
  if (st == 0) {     // stream-0 waves: combine, write out, GN partials
#pragma unroll
    for (int mt = 0; mt < 4; ++mt) {
      float i1[4];
#pragma unroll
      for (int r = 0; r < 4; ++r) i1[r] = 1.f / lacc[mt][r];
#pragma unroll
      for (int nt8 = 0; nt8 < 8; ++nt8)
#pragma unroll
        for (int r = 0; r < 4; ++r) {
          int rl = qh * 64 + mt * 16 + quad * 4 + r;
          int col = nt8 * 16 + l16;
          float o2 = __uint_as_float((unsigned int)O2[rl * 128 + col] << 16);
          float o = acc[mt][nt8][r] * i1[r] - o2;
          out[((size_t)bh * S + q0 + rl) * D + col] = o;
          sum += o; ssq += o * o;
        }
    }
#pragma unroll
    for (int off = 32; off >= 1; off >>= 1) {
      sum += __shfl_xor(sum, off, 64);
      ssq += __shfl_xor(ssq, off, 64);
    }
    if (lane == 0) { sred[wave][0] = sum; sred[wave][1] = ssq; }
  }
  __syncthreads();
  if (tid == 0) {
    int idx = bh * 16 + qb;
    wsf[64 + idx * 2] = sred[0][0] + sred[1][0];
    wsf[64 + idx * 2 + 1] = sred[0][1] + sred[1][1];
  }
}

// ---------------- kernel 2: group norm (in-place on out) ----------------
__global__ void gn_kernel(float* __restrict__ out, const float* __restrict__ gw,
                          const float* __restrict__ gb, const float* __restrict__ wsf) {
  const int bh = blockIdx.x, part = blockIdx.y;
  const int h = bh & (H - 1);
  float sum = 0.f, ssq = 0.f;
  for (int j = 0; j < 16; ++j) {
    sum += wsf[64 + (bh * 16 + j) * 2];
    ssq += wsf[64 + (bh * 16 + j) * 2 + 1];
  }
  const float invn = 1.f / (float)(S * D);
  const float mean = sum * invn;
  const float var = ssq * invn - mean * mean;
  const float rstd = rsqrtf(var + GN_EPS);
  const float outscale = 1.f - LAM_INIT;
  const float4* g4 = (const float4*)(gw + h * D);
  const float4* b4 = (const float4*)(gb + h * D);
  float4* o4 = (float4*)(out + (size_t)bh * S * D);
  const int chunks_per = (S * D / 4) / 32;   // 2048
  const int c0 = part * chunks_per;
  for (int c = c0 + threadIdx.x; c < c0 + chunks_per; c += 256) {
    float4 vv = o4[c];
    int d4 = c & 31;
    float4 g = g4[d4], bb = b4[d4];
    vv.x = ((vv.x - mean) * rstd * g.x + bb.x) * outscale;
    vv.y = ((vv.y - mean) * rstd * g.y + bb.y) * outscale;
    vv.z = ((vv.z - mean) * rstd * g.z + bb.z) * outscale;
    vv.w = ((vv.w - mean) * rstd * g.w + bb.w) * outscale;
    o4[c] = vv;
  }
}

extern "C" void kernel_launch(void* const* d_in, const int* in_sizes, int n_in,
                              void* d_out, int out_size, void* d_ws, size_t ws_size,
                              hipStream_t stream) {
  (void)in_sizes; (void)n_in; (void)out_size; (void)ws_size;
  const float* q   = (const float*)d_in[0];
  const float* k   = (const float*)d_in[1];
  const float* v   = (const float*)d_in[2];
  const float* lq1 = (const float*)d_in[3];
  const float* lq2 = (const float*)d_in[4];
  const float* lk1 = (const float*)d_in[5];
  const float* lk2 = (const float*)d_in[6];
  const float* gw  = (const float*)d_in[7];
  const float* gb  = (const float*)d_in[8];
  float* out = (float*)d_out;
  float* wsf = (float*)d_ws;
  unsigned short* vtg = (unsigned short*)((char*)d_ws + 8192);
  unsigned short* kbf = (unsigned short*)((char*)d_ws + 8192 + (size_t)BH * D * S * 2);

  prep_kernel<<<dim3(S / 128, BH), dim3(256), 0, stream>>>(k, v, lq1, lq2, lk1, lk2, kbf, vtg, wsf);
  attn_kernel<<<dim3(BH, S / QTILE), dim3(256), 0, stream>>>(q, kbf, vtg, wsf, out);
  gn_kernel<<<dim3(BH, 32), dim3(256), 0, stream>>>(out, gw, gb, wsf);
}